// Round 6
// baseline (2904.288 us; speedup 1.0000x reference)
//
#include <hip/hip_runtime.h>
#include <hip/hip_bf16.h>
#include <stdint.h>

#define NB 8
#define NN 8192
#define NC 64
#define NS 2048
#define NK 32
#define NCOL (NB*NS*NK)   // 524288 columns (b,s,n)

typedef float v2f __attribute__((ext_vector_type(2)));

// ---------- bf16 helpers (RNE) ----------
__device__ __forceinline__ unsigned short f2bf(float x) {
    union { float f; unsigned u; } c; c.f = x;
    unsigned r = c.u + 0x7fffu + ((c.u >> 16) & 1u);
    return (unsigned short)(r >> 16);
}
__device__ __forceinline__ float bf2f(unsigned v16) {
    union { float f; unsigned u; } c; c.u = v16 << 16;
    return c.f;
}

// ---------- DPP cross-lane helpers (VALU-speed, no LDS) ----------
template<int CTRL>
__device__ __forceinline__ float dpp_add_f32(float x) {   // zero-fill identity
    int o = __builtin_amdgcn_update_dpp(0, __float_as_int(x), CTRL, 0xf, 0xf, true);
    return x + __int_as_float(o);
}
template<int CTRL>
__device__ __forceinline__ float dpp_max_f32(float x) {   // self identity
    int o = __builtin_amdgcn_update_dpp(__float_as_int(x), __float_as_int(x), CTRL, 0xf, 0xf, false);
    return fmaxf(x, __int_as_float(o));
}
template<int CTRL>
__device__ __forceinline__ float dpp_min_f32(float x) {   // self identity
    int o = __builtin_amdgcn_update_dpp(__float_as_int(x), __float_as_int(x), CTRL, 0xf, 0xf, false);
    return fminf(x, __int_as_float(o));
}
__device__ __forceinline__ v2f relu2(v2f v) {
    v.x = fmaxf(v.x, 0.f); v.y = fmaxf(v.y, 0.f); return v;
}

// ============================================================================
// 1) Furthest point sampling with EXACT bbox pruning.
//    One block/batch, 512 threads, 16 sorted-consecutive points each.
//    Setup: 8x8x8 counting-sort of points into LDS (order within a bin is
//    nondeterministic but results are bit-exact: fminf is exactly
//    associative/commutative and skips are proven no-ops).
//    Per iteration:
//      dlb = fp32 lower bound on d(new_pt, chunk) built from the SAME
//      monotone op chain as d (contract off). If dlb >= bound (exact chunk
//      max of dmin), the whole 16-pt update is a bitwise no-op -> skip.
//      Argmax = DPP f32 max of bounds -> 8 wave maxes in LDS -> gmax.
//      Threads with bound==gmax resolve ties by ORIGINAL index via
//      atomicMin on (orig_idx<<13 | sorted_pos). Two barriers/iter,
//      parity-double-buffered LDS slots.
// ============================================================================
__global__ __launch_bounds__(512, 1) void fps_kernel(const float* __restrict__ xyz,
    float* __restrict__ new_xyz, float* __restrict__ out_newxyz)
{
#pragma clang fp contract(off)
    const int b = blockIdx.x;
    const int tid = threadIdx.x;
    const float* xb = xyz + (size_t)b * NN * 3;
    __shared__ float sx[NN], sy[NN], sz[NN];     // sorted coords (96 KB)
    __shared__ int   si[NN];                     // sorted -> original idx (32 KB)
    __shared__ int   bins[512];
    __shared__ float s_bnd[2][8];
    __shared__ int   s_win[2];
    // ---- histogram ----
    bins[tid] = 0;
    if (tid == 0) { s_win[0] = 0x7fffffff; s_win[1] = 0x7fffffff; }
    __syncthreads();
    int cell[16];
#pragma unroll
    for (int j = 0; j < 16; ++j) {
        int p = j * 512 + tid;
        float x = xb[p*3+0], y = xb[p*3+1], z = xb[p*3+2];
        int ix = min(7, max(0, (int)(x * 8.f)));
        int iy = min(7, max(0, (int)(y * 8.f)));
        int iz = min(7, max(0, (int)(z * 8.f)));
        int c = (iz << 6) | (iy << 3) | ix;
        cell[j] = c;
        atomicAdd(&bins[c], 1);
    }
    __syncthreads();
    // ---- exclusive scan (runs once; serial is fine) ----
    if (tid == 0) {
        int acc = 0;
        for (int i = 0; i < 512; ++i) { int c = bins[i]; bins[i] = acc; acc += c; }
    }
    __syncthreads();
    // ---- scatter ----
#pragma unroll
    for (int j = 0; j < 16; ++j) {
        int p = j * 512 + tid;
        int pos = atomicAdd(&bins[cell[j]], 1);
        sx[pos] = xb[p*3+0]; sy[pos] = xb[p*3+1]; sz[pos] = xb[p*3+2];
        si[pos] = p;
    }
    __syncthreads();
    // ---- load chunk (16 consecutive sorted points) + bbox ----
    const int base = tid * 16;
    float px[16], py[16], pz[16], dmin[16];
    float bxmin = 1e30f, bxmax = -1e30f;
    float bymin = 1e30f, bymax = -1e30f;
    float bzmin = 1e30f, bzmax = -1e30f;
#pragma unroll
    for (int j = 0; j < 16; ++j) {
        float x = sx[base+j], y = sy[base+j], z = sz[base+j];
        px[j] = x; py[j] = y; pz[j] = z; dmin[j] = 1e10f;
        bxmin = fminf(bxmin, x); bxmax = fmaxf(bxmax, x);
        bymin = fminf(bymin, y); bymax = fmaxf(bymax, y);
        bzmin = fminf(bzmin, z); bzmax = fmaxf(bzmax, z);
    }
    float bound = 1e10f;
    float lx = xb[0], ly = xb[1], lz = xb[2];    // selection 0 = point 0
    if (tid == 0) {
        float* nw = new_xyz + (size_t)b * NS * 3;
        float* ow = out_newxyz + (size_t)b * NS * 3;
        nw[0] = lx; nw[1] = ly; nw[2] = lz;
        ow[0] = lx; ow[1] = ly; ow[2] = lz;
    }
    for (int i = 1; i < NS; ++i) {
        const int par = i & 1;
        // rigorous fp32 lower bound on d(last, any p in chunk):
        // same op order as d; fl is monotone => d >= dlb exactly.
        float dxl = fmaxf(fmaxf(bxmin - lx, lx - bxmax), 0.f);
        float dyl = fmaxf(fmaxf(bymin - ly, ly - bymax), 0.f);
        float dzl = fmaxf(fmaxf(bzmin - lz, lz - bzmax), 0.f);
        float dlb = (dxl*dxl + dyl*dyl) + dzl*dzl;
        if (dlb < bound) {                       // else: update provably no-op
            float nb = -1.f;
#pragma unroll
            for (int j = 0; j < 16; ++j) {
                float dx = px[j] - lx;
                float dy = py[j] - ly;
                float dz = pz[j] - lz;
                float d = (dx*dx + dy*dy) + dz*dz;   // exact eval order
                float dm = fminf(dmin[j], d);
                dmin[j] = dm;
                nb = fmaxf(nb, dm);
            }
            bound = nb;                          // exact chunk max, always
        }
        // wave64 max of bounds via DPP -> lane 63
        float wmax = bound;
        wmax = dpp_max_f32<0x111>(wmax);   // row_shr:1
        wmax = dpp_max_f32<0x112>(wmax);   // row_shr:2
        wmax = dpp_max_f32<0x114>(wmax);   // row_shr:4
        wmax = dpp_max_f32<0x118>(wmax);   // row_shr:8
        wmax = dpp_max_f32<0x142>(wmax);   // row_bcast:15
        wmax = dpp_max_f32<0x143>(wmax);   // row_bcast:31
        if ((tid & 63) == 63) s_bnd[par][tid >> 6] = wmax;
        __syncthreads();                         // barrier 1
        const float* bb = s_bnd[par];
        float gmax = fmaxf(fmaxf(fmaxf(bb[0], bb[1]), fmaxf(bb[2], bb[3])),
                           fmaxf(fmaxf(bb[4], bb[5]), fmaxf(bb[6], bb[7])));
        if (bound == gmax) {                     // candidate chunk(s)
            int best = 0x7fffffff, bestp = 0;
#pragma unroll
            for (int j = 0; j < 16; ++j) {
                int oi = si[base + j];
                if (dmin[j] == gmax && oi < best) { best = oi; bestp = base + j; }
            }
            atomicMin(&s_win[par], (best << 13) | bestp);  // smallest orig idx
        }
        if (tid == 0) s_win[par ^ 1] = 0x7fffffff;         // reset other slot
        __syncthreads();                         // barrier 2
        const int pos = s_win[par] & 8191;
        lx = sx[pos]; ly = sy[pos]; lz = sz[pos];
        if (tid == 0) {
            float* nw = new_xyz + ((size_t)b * NS + i) * 3;
            float* ow = out_newxyz + ((size_t)b * NS + i) * 3;
            nw[0] = lx; nw[1] = ly; nw[2] = lz;
            ow[0] = lx; ow[1] = ly; ow[2] = lz;
        }
    }
}

// ============================================================================
// 2) Transpose features (B,C,N) -> (B,N,C) for contiguous per-point gathers.
// ============================================================================
__global__ __launch_bounds__(256) void transpose_kernel(const float* __restrict__ f,
    float* __restrict__ ft)
{
    __shared__ float tile[64][65];
    int b = blockIdx.y;
    int p0 = blockIdx.x * 64;
    for (int k = threadIdx.x; k < 64*64; k += 256) {
        int c = k >> 6, p = k & 63;
        tile[c][p] = f[((size_t)b * NC + c) * NN + p0 + p];
    }
    __syncthreads();
    for (int k = threadIdx.x; k < 64*64; k += 256) {
        int p = k >> 6, c = k & 63;
        ft[((size_t)b * NN + p0 + p) * NC + c] = tile[c][p];
    }
}

// ============================================================================
// 3) Ball query: one wave per (b,s) query. First 32 smallest in-ball indices,
//    pad with first. r2 must be float(0.2*0.2) = 0.0399999991 (not 0.2f*0.2f).
// ============================================================================
__global__ __launch_bounds__(256) void ballquery_kernel(const float* __restrict__ xyz,
    const float* __restrict__ new_xyz, int* __restrict__ idx)
{
#pragma clang fp contract(off)
    const int q = blockIdx.x * 4 + (threadIdx.x >> 6);
    const int lane = threadIdx.x & 63;
    const int b = q >> 11;
    const float r2 = (float)(0.2 * 0.2);
    const float* xb = xyz + (size_t)b * NN * 3;
    const float* nx = new_xyz + (size_t)q * 3;
    float qx = nx[0], qy = nx[1], qz = nx[2];
    int cnt = 0, first = -1;
    int* out = idx + (size_t)q * NK;
    for (int base = 0; base < NN; base += 64) {
        int p = base + lane;
        float x = xb[p*3+0], y = xb[p*3+1], z = xb[p*3+2];
        float dx = qx - x, dy = qy - y, dz = qz - z;
        float d2 = (dx*dx + dy*dy) + dz*dz;
        bool in = d2 < r2;
        unsigned long long m = __ballot(in);
        if (m) {
            if (first < 0) first = base + __builtin_ctzll(m);
            if (in) {
                int rank = cnt + __popcll(m & ((1ull << lane) - 1ull));
                if (rank < NK) out[rank] = p;
            }
            cnt += __popcll(m);
            if (cnt >= NK) break;
        }
    }
    for (int k = cnt + lane; k < NK; k += 64) out[k] = first;  // cnt>=1 always
}

// ============================================================================
// 4) Layer 1: h1 = W1(64x67) @ g. v2f packed FMAs; h computed in two halves
//    of 32 outputs to keep VGPR below spill point. h1 bf16.
// ============================================================================
__global__ __launch_bounds__(256, 2) void layer1_kernel(const float* __restrict__ xyz,
    const float* __restrict__ new_xyz, const int* __restrict__ idx,
    const float* __restrict__ ft, const float* __restrict__ W1,
    unsigned short* __restrict__ h1)
{
    const int col = blockIdx.x * 256 + threadIdx.x;
    const int b = col >> 16;
    const int s = (col >> 5) & 2047;
    const int p = idx[col];
    v2f g[34];
    float* gf = (float*)g;
    {
        const float* nx = new_xyz + ((size_t)(b * NS + s)) * 3;
        const float* xp = xyz + ((size_t)(b * NN + p)) * 3;
        gf[0] = xp[0] - nx[0]; gf[1] = xp[1] - nx[1]; gf[2] = xp[2] - nx[2];
    }
    const float4* fp = (const float4*)(ft + ((size_t)(b * NN + p)) * NC);
#pragma unroll
    for (int c4 = 0; c4 < 16; ++c4) {
        float4 v = fp[c4];
        gf[3 + 4*c4 + 0] = v.x; gf[3 + 4*c4 + 1] = v.y;
        gf[3 + 4*c4 + 2] = v.z; gf[3 + 4*c4 + 3] = v.w;
    }
    gf[67] = 0.f;
    uint4* dst = (uint4*)(h1 + (size_t)col * 64);
#pragma unroll
    for (int half = 0; half < 2; ++half) {
        float h[32];
#pragma unroll 4
        for (int o16 = 0; o16 < 32; ++o16) {
            const float* w = W1 + (half*32 + o16) * 67;
            v2f acc; acc.x = 0.f; acc.y = 0.f;
#pragma unroll
            for (int k = 0; k < 33; ++k) {
                v2f wv; wv.x = w[2*k]; wv.y = w[2*k+1];
                acc = wv * g[k] + acc;                    // v_pk_fma_f32
            }
            h[o16] = fmaf(w[66], gf[66], acc.x + acc.y);
        }
#pragma unroll
        for (int k = 0; k < 4; ++k) {
            uint4 v;
            v.x = (unsigned)f2bf(h[8*k+0]) | ((unsigned)f2bf(h[8*k+1]) << 16);
            v.y = (unsigned)f2bf(h[8*k+2]) | ((unsigned)f2bf(h[8*k+3]) << 16);
            v.z = (unsigned)f2bf(h[8*k+4]) | ((unsigned)f2bf(h[8*k+5]) << 16);
            v.w = (unsigned)f2bf(h[8*k+6]) | ((unsigned)f2bf(h[8*k+7]) << 16);
            dst[half*4 + k] = v;
        }
    }
}

// ============================================================================
// 5) Stats pass over a bf16 [col][64] tensor: per-channel sum / sumsq.
// ============================================================================
__global__ __launch_bounds__(256) void stats_kernel(const unsigned short* __restrict__ h,
    float* __restrict__ sums)
{
    __shared__ float ls[64], lq[64];
    const int tid = threadIdx.x;
    if (tid < 64) { ls[tid] = 0.f; lq[tid] = 0.f; }
    __syncthreads();
    float s[8] = {0,0,0,0,0,0,0,0}, q[8] = {0,0,0,0,0,0,0,0};
    const int gt = blockIdx.x * 256 + tid;
    const int G = gridDim.x * 256;            // multiple of 8 -> channel phase fixed
    const uint4* src = (const uint4*)h;
    const int nvec = NCOL * 8;                 // uint4s (8 bf16 each)
    for (int i = gt; i < nvec; i += G) {
        uint4 v = src[i];
        float f0 = bf2f(v.x & 0xffffu), f1 = bf2f(v.x >> 16);
        float f2 = bf2f(v.y & 0xffffu), f3 = bf2f(v.y >> 16);
        float f4 = bf2f(v.z & 0xffffu), f5 = bf2f(v.z >> 16);
        float f6 = bf2f(v.w & 0xffffu), f7 = bf2f(v.w >> 16);
        s[0] += f0; q[0] = fmaf(f0, f0, q[0]);
        s[1] += f1; q[1] = fmaf(f1, f1, q[1]);
        s[2] += f2; q[2] = fmaf(f2, f2, q[2]);
        s[3] += f3; q[3] = fmaf(f3, f3, q[3]);
        s[4] += f4; q[4] = fmaf(f4, f4, q[4]);
        s[5] += f5; q[5] = fmaf(f5, f5, q[5]);
        s[6] += f6; q[6] = fmaf(f6, f6, q[6]);
        s[7] += f7; q[7] = fmaf(f7, f7, q[7]);
    }
    const int obase = (tid & 7) * 8;
#pragma unroll
    for (int j = 0; j < 8; ++j) {
        atomicAdd(&ls[obase + j], s[j]);
        atomicAdd(&lq[obase + j], q[j]);
    }
    __syncthreads();
    if (tid < 64) {
        atomicAdd(&sums[tid*2+0], ls[tid]);
        atomicAdd(&sums[tid*2+1], lq[tid]);
    }
}

// ============================================================================
// 6) Finalize BN params. Layout: ab[c] = a_c (scale), ab[nch+c] = b_c (shift)
//    so the apply step can use packed v2f math.
// ============================================================================
__global__ void finalize_kernel(const float* __restrict__ sums,
    const float* __restrict__ gamma, const float* __restrict__ beta,
    float* __restrict__ ab, int nch)
{
    int c = threadIdx.x;
    if (c < nch) {
        const float invM = 1.0f / 524288.0f;
        float mu = sums[c*2] * invM;
        float var = sums[c*2+1] * invM - mu * mu;
        float a = gamma[c] / sqrtf(var + 1e-5f);
        ab[c] = a;
        ab[nch + c] = fmaf(-mu, a, beta[c]);
    }
}

// ============================================================================
// 7) Layer 2: g2 = relu(BN1(h1)); h2 = W2(64x64) @ g2. Packed FMAs, halves.
// ============================================================================
__global__ __launch_bounds__(256, 2) void layer2_kernel(const unsigned short* __restrict__ h1,
    const float* __restrict__ ab1, const float* __restrict__ W2,
    unsigned short* __restrict__ h2)
{
    const int col = blockIdx.x * 256 + threadIdx.x;
    const uint4* src = (const uint4*)(h1 + (size_t)col * 64);
    v2f g[32];
    float* gf = (float*)g;
#pragma unroll
    for (int k = 0; k < 8; ++k) {
        uint4 v = src[k];
        gf[8*k+0] = bf2f(v.x & 0xffffu); gf[8*k+1] = bf2f(v.x >> 16);
        gf[8*k+2] = bf2f(v.y & 0xffffu); gf[8*k+3] = bf2f(v.y >> 16);
        gf[8*k+4] = bf2f(v.z & 0xffffu); gf[8*k+5] = bf2f(v.z >> 16);
        gf[8*k+6] = bf2f(v.w & 0xffffu); gf[8*k+7] = bf2f(v.w >> 16);
    }
    const v2f* a2 = (const v2f*)ab1;
    const v2f* b2 = (const v2f*)(ab1 + 64);
#pragma unroll
    for (int k = 0; k < 32; ++k)
        g[k] = relu2(a2[k] * g[k] + b2[k]);               // pk_fma + pk_max
    uint4* dst = (uint4*)(h2 + (size_t)col * 64);
#pragma unroll
    for (int half = 0; half < 2; ++half) {
        float h[32];
#pragma unroll 4
        for (int o16 = 0; o16 < 32; ++o16) {
            const float* w = W2 + ((half*32 + o16) << 6);
            v2f acc; acc.x = 0.f; acc.y = 0.f;
#pragma unroll
            for (int k = 0; k < 32; ++k) {
                v2f wv; wv.x = w[2*k]; wv.y = w[2*k+1];
                acc = wv * g[k] + acc;
            }
            h[o16] = acc.x + acc.y;
        }
#pragma unroll
        for (int k = 0; k < 4; ++k) {
            uint4 v;
            v.x = (unsigned)f2bf(h[8*k+0]) | ((unsigned)f2bf(h[8*k+1]) << 16);
            v.y = (unsigned)f2bf(h[8*k+2]) | ((unsigned)f2bf(h[8*k+3]) << 16);
            v.z = (unsigned)f2bf(h[8*k+4]) | ((unsigned)f2bf(h[8*k+5]) << 16);
            v.w = (unsigned)f2bf(h[8*k+6]) | ((unsigned)f2bf(h[8*k+7]) << 16);
            dst[half*4 + k] = v;
        }
    }
}

// ============================================================================
// 8) Layer 3: g3 = relu(BN2(h2)); h3 = W3(128x64) @ g3; per-(b,s) max/min over
//    n=32 (lanes) + channel stats — all reductions via DPP (no ds ops).
// ============================================================================
__global__ __launch_bounds__(256, 2) void layer3_kernel(const unsigned short* __restrict__ h2,
    const float* __restrict__ ab2, const float* __restrict__ W3,
    float* __restrict__ hmax, float* __restrict__ hmin, float* __restrict__ sums3)
{
    __shared__ float ls[128], lq[128];
    const int tid = threadIdx.x;
    if (tid < 128) { ls[tid] = 0.f; lq[tid] = 0.f; }
    __syncthreads();
    const int col = blockIdx.x * 256 + tid;
    const int q = col >> 5;            // group (b*2048+s); lanes 0-31 / 32-63
    const uint4* src = (const uint4*)(h2 + (size_t)col * 64);
    v2f g[32];
    float* gf = (float*)g;
#pragma unroll
    for (int k = 0; k < 8; ++k) {
        uint4 v = src[k];
        gf[8*k+0] = bf2f(v.x & 0xffffu); gf[8*k+1] = bf2f(v.x >> 16);
        gf[8*k+2] = bf2f(v.y & 0xffffu); gf[8*k+3] = bf2f(v.y >> 16);
        gf[8*k+4] = bf2f(v.z & 0xffffu); gf[8*k+5] = bf2f(v.z >> 16);
        gf[8*k+6] = bf2f(v.w & 0xffffu); gf[8*k+7] = bf2f(v.w >> 16);
    }
    const v2f* a2 = (const v2f*)ab2;
    const v2f* b2 = (const v2f*)(ab2 + 64);
#pragma unroll
    for (int k = 0; k < 32; ++k)
        g[k] = relu2(a2[k] * g[k] + b2[k]);
    const bool leader = ((tid & 31) == 31);
#pragma unroll 2
    for (int o = 0; o < 128; ++o) {
        const float* w = W3 + (o << 6);
        v2f acc; acc.x = 0.f; acc.y = 0.f;
#pragma unroll
        for (int k = 0; k < 32; ++k) {
            v2f wv; wv.x = w[2*k]; wv.y = w[2*k+1];
            acc = wv * g[k] + acc;
        }
        float hv = acc.x + acc.y;
        float sm = hv, sq = hv*hv, mx = hv, mn = hv;
        sm = dpp_add_f32<0x111>(sm); sq = dpp_add_f32<0x111>(sq);
        mx = dpp_max_f32<0x111>(mx); mn = dpp_min_f32<0x111>(mn);
        sm = dpp_add_f32<0x112>(sm); sq = dpp_add_f32<0x112>(sq);
        mx = dpp_max_f32<0x112>(mx); mn = dpp_min_f32<0x112>(mn);
        sm = dpp_add_f32<0x114>(sm); sq = dpp_add_f32<0x114>(sq);
        mx = dpp_max_f32<0x114>(mx); mn = dpp_min_f32<0x114>(mn);
        sm = dpp_add_f32<0x118>(sm); sq = dpp_add_f32<0x118>(sq);
        mx = dpp_max_f32<0x118>(mx); mn = dpp_min_f32<0x118>(mn);
        sm = dpp_add_f32<0x142>(sm); sq = dpp_add_f32<0x142>(sq);
        mx = dpp_max_f32<0x142>(mx); mn = dpp_min_f32<0x142>(mn);
        if (leader) {
            hmax[(size_t)o * 16384 + q] = mx;
            hmin[(size_t)o * 16384 + q] = mn;
            atomicAdd(&ls[o], sm);
            atomicAdd(&lq[o], sq);
        }
    }
    __syncthreads();
    if (tid < 128) {
        atomicAdd(&sums3[tid*2+0], ls[tid]);
        atomicAdd(&sums3[tid*2+1], lq[tid]);
    }
}

// ============================================================================
// 9) Final: feats[b,o,s] = relu(a3*(a3>=0 ? max : min) + c3)
// ============================================================================
__global__ __launch_bounds__(256) void final_kernel(const float* __restrict__ hmax,
    const float* __restrict__ hmin, const float* __restrict__ ab3,
    float* __restrict__ out)
{
    const int t = blockIdx.x * 256 + threadIdx.x;   // (b,o,s), s fastest
    const int s = t & 2047;
    const int o = (t >> 11) & 127;
    const int b = t >> 18;
    const int q = (b << 11) + s;
    float a = ab3[o], c = ab3[128 + o];
    float h = (a >= 0.f) ? hmax[(size_t)o * 16384 + q] : hmin[(size_t)o * 16384 + q];
    out[t] = fmaxf(fmaf(a, h, c), 0.f);
}

// ============================================================================
extern "C" void kernel_launch(void* const* d_in, const int* in_sizes, int n_in,
                              void* d_out, int out_size, void* d_ws, size_t ws_size,
                              hipStream_t stream) {
    (void)in_sizes; (void)n_in; (void)out_size; (void)ws_size;
    const float* xyz      = (const float*)d_in[0];
    const float* features = (const float*)d_in[1];
    const float* W1 = (const float*)d_in[2];
    const float* g1 = (const float*)d_in[3];
    const float* b1 = (const float*)d_in[4];
    const float* W2 = (const float*)d_in[5];
    const float* g2 = (const float*)d_in[6];
    const float* b2 = (const float*)d_in[7];
    const float* W3 = (const float*)d_in[8];
    const float* g3 = (const float*)d_in[9];
    const float* b3 = (const float*)d_in[10];

    char* ws = (char*)d_ws;
    float*          new_xyz = (float*)(ws + 0);                  // 196608 B
    int*            idx     = (int*)(ws + 196608);               // 2097152 B
    float*          ft      = (float*)(ws + 2293760);            // 16777216 B
    unsigned short* h1      = (unsigned short*)(ws + 19070976);  // 67108864 B
    unsigned short* h2      = (unsigned short*)(ws + 86179840);  // 67108864 B
    float*          hmax    = (float*)(ws + 153288704);          // 8388608 B
    float*          hmin    = (float*)(ws + 161677312);          // 8388608 B
    float*          sums    = (float*)(ws + 170065920);          // 2048 B (zeroed)
    float*          ab      = (float*)(ws + 170067968);          // 2048 B
    float* sums1 = sums;        float* ab1 = ab;
    float* sums2 = sums + 128;  float* ab2 = ab + 128;
    float* sums3 = sums + 256;  float* ab3 = ab + 256;

    float* out_newxyz = (float*)d_out;            // B*NS*3 = 49152 floats
    float* out_feats  = (float*)d_out + 49152;    // B*128*NS floats

    hipMemsetAsync(sums, 0, 2048, stream);

    fps_kernel<<<NB, 512, 0, stream>>>(xyz, new_xyz, out_newxyz);
    transpose_kernel<<<dim3(NN/64, NB), 256, 0, stream>>>(features, ft);
    ballquery_kernel<<<(NB*NS)/4, 256, 0, stream>>>(xyz, new_xyz, idx);
    layer1_kernel<<<NCOL/256, 256, 0, stream>>>(xyz, new_xyz, idx, ft, W1, h1);
    stats_kernel<<<1024, 256, 0, stream>>>(h1, sums1);
    finalize_kernel<<<1, 128, 0, stream>>>(sums1, g1, b1, ab1, 64);
    layer2_kernel<<<NCOL/256, 256, 0, stream>>>(h1, ab1, W2, h2);
    stats_kernel<<<1024, 256, 0, stream>>>(h2, sums2);
    finalize_kernel<<<1, 128, 0, stream>>>(sums2, g2, b2, ab2, 64);
    layer3_kernel<<<NCOL/256, 256, 0, stream>>>(h2, ab2, W3, hmax, hmin, sums3);
    finalize_kernel<<<1, 128, 0, stream>>>(sums3, g3, b3, ab3, 128);
    final_kernel<<<(NB*128*NS)/256, 256, 0, stream>>>(hmax, hmin, ab3, out_feats);
}